// Round 1
// baseline (90.489 us; speedup 1.0000x reference)
//
#include <hip/hip_runtime.h>
#include <hip/hip_bf16.h>
#include <stdint.h>

#define LL 2048   // sequence length
#define NB 16     // batch
#define DD 256    // din = dout

typedef __bf16 bf16x8 __attribute__((ext_vector_type(8)));
typedef float f32x4 __attribute__((ext_vector_type(4)));

__device__ __forceinline__ unsigned short f2bf(float f) {
    uint32_t u = __float_as_uint(f);
    u = (u + 0x7FFFu + ((u >> 16) & 1u)) >> 16;   // RNE
    return (unsigned short)u;
}

__device__ __forceinline__ float bf2f(unsigned short v) {
    return __uint_as_float(((uint32_t)v) << 16);
}

__device__ __forceinline__ void gload16(const void* g, void* l) {
    __builtin_amdgcn_global_load_lds(
        (const __attribute__((address_space(1))) void*)g,
        (__attribute__((address_space(3))) void*)l,
        16, 0, 0);
}

// ---------------------------------------------------------------------------
// Kernel 1: per-row degree -> dinv, plus graph f32 -> bf16 conversion.
// graph is symmetric so column sums == row sums. deg includes +1 self loop.
// ---------------------------------------------------------------------------
__global__ __launch_bounds__(256) void prep_graph(
        const float* __restrict__ graph, float* __restrict__ dinv,
        unsigned short* __restrict__ gbf) {
    int r = blockIdx.x;
    int t = threadIdx.x;
    const float4* row = (const float4*)(graph + (size_t)r * LL);
    float4 v0 = row[t * 2 + 0];
    float4 v1 = row[t * 2 + 1];
    float s = v0.x + v0.y + v0.z + v0.w + v1.x + v1.y + v1.z + v1.w;

    unsigned short* gd = gbf + (size_t)r * LL + t * 8;
    ushort4 p0 = make_ushort4(f2bf(v0.x), f2bf(v0.y), f2bf(v0.z), f2bf(v0.w));
    ushort4 p1 = make_ushort4(f2bf(v1.x), f2bf(v1.y), f2bf(v1.z), f2bf(v1.w));
    *(ushort4*)(gd + 0) = p0;
    *(ushort4*)(gd + 4) = p1;

    // block reduce (4 waves)
    #pragma unroll
    for (int off = 32; off > 0; off >>= 1) s += __shfl_down(s, off, 64);
    __shared__ float red[4];
    if ((t & 63) == 0) red[t >> 6] = s;
    __syncthreads();
    if (t == 0) {
        float deg = red[0] + red[1] + red[2] + red[3] + 1.0f;  // + self loop
        dinv[r] = 1.0f / sqrtf(deg);
    }
}

// ---------------------------------------------------------------------------
// Kernel 2: Wt[o][d] = bf16(W[d][o])   (tiny: 64K elements)
// ---------------------------------------------------------------------------
__global__ __launch_bounds__(256) void prep_w(
        const float* __restrict__ W, unsigned short* __restrict__ Wt) {
    int tid = blockIdx.x * 256 + threadIdx.x;   // 0..65535
    int d = tid >> 8, o = tid & 255;
    Wt[o * DD + d] = f2bf(W[tid]);
}

// ---------------------------------------------------------------------------
// Kernel 3: Pt[b*256+o][m] = bf16( dinv[m] * sum_d x[b,m,d] * W[d,o] )
// M = 32768 (b*2048+m), N = 256 (o), K = 256 (d). 128x128 tile, 4 waves.
// ---------------------------------------------------------------------------
__global__ __launch_bounds__(256) void linear_kernel(
        const float* __restrict__ x, const unsigned short* __restrict__ Wt,
        const float* __restrict__ dinv, unsigned short* __restrict__ Pt) {
    __shared__ __align__(16) unsigned short Al[128][64];
    __shared__ __align__(16) unsigned short Bl[128][64];
    int t = threadIdx.x;
    int w = t >> 6, ln = t & 63;
    int m0 = blockIdx.x * 128;            // global row (b*2048 + m)
    int n0 = blockIdx.y * 128;            // o offset
    int b  = m0 >> 11;
    int ml0 = m0 & (LL - 1);
    int wm = w >> 1, wn = w & 1;
    int lr = ln & 15, lg = ln >> 4;

    f32x4 acc[4][4] = {};

    for (int k0 = 0; k0 < DD; k0 += 64) {
        // stage A: x[m0..+128][k0..+64] f32 -> bf16 (reg staged)
        #pragma unroll
        for (int it = 0; it < 8; ++it) {
            int c = it * 256 + t;                  // 2048 chunks of 4 f32
            int row = c >> 4, col = (c & 15) * 4;
            float4 v = *(const float4*)(x + (size_t)(m0 + row) * DD + k0 + col);
            *(ushort4*)(&Al[row][col]) =
                make_ushort4(f2bf(v.x), f2bf(v.y), f2bf(v.z), f2bf(v.w));
        }
        // stage B: Wt rows n0..+128, cols k0..+64 (already bf16), async
        #pragma unroll
        for (int it = 0; it < 4; ++it) {
            int c = it * 256 + t;                  // 1024 chunks of 8 bf16
            const unsigned short* g = Wt + (size_t)(n0 + (c >> 3)) * DD + k0 + (c & 7) * 8;
            unsigned short* lp = &Bl[0][0] + (size_t)(it * 256 + w * 64) * 8;
            gload16(g, lp);
        }
        __syncthreads();
        #pragma unroll
        for (int kk = 0; kk < 64; kk += 32) {
            bf16x8 af[4], bq[4];
            #pragma unroll
            for (int i = 0; i < 4; ++i)
                af[i] = *(const bf16x8*)&Al[wm * 64 + i * 16 + lr][kk + lg * 8];
            #pragma unroll
            for (int j = 0; j < 4; ++j)
                bq[j] = *(const bf16x8*)&Bl[wn * 64 + j * 16 + lr][kk + lg * 8];
            #pragma unroll
            for (int i = 0; i < 4; ++i)
                #pragma unroll
                for (int j = 0; j < 4; ++j)
                    acc[i][j] = __builtin_amdgcn_mfma_f32_16x16x32_bf16(
                        af[i], bq[j], acc[i][j], 0, 0, 0);
        }
        __syncthreads();
    }

    // epilogue: Pt[(b*256+o)][m] = bf16(dinv[m] * acc)
    #pragma unroll
    for (int i = 0; i < 4; ++i) {
        int ml = ml0 + wm * 64 + i * 16 + lg * 4;   // 4 consecutive m
        float4 dv = *(const float4*)(dinv + ml);
        #pragma unroll
        for (int j = 0; j < 4; ++j) {
            int o = n0 + wn * 64 + j * 16 + lr;
            ushort4 pk = make_ushort4(f2bf(dv.x * acc[i][j][0]),
                                      f2bf(dv.y * acc[i][j][1]),
                                      f2bf(dv.z * acc[i][j][2]),
                                      f2bf(dv.w * acc[i][j][3]));
            *(ushort4*)(Pt + ((size_t)(b * DD + o)) * LL + ml) = pk;
        }
    }
}

// ---------------------------------------------------------------------------
// Kernel 4: S = gbf @ Pt^T  (M=2048 l, N=4096 n'=b*256+o, K=2048 m),
// epilogue: out = relu(dinv[l]*(S + Pt[n'][l]) + bias[o]) + x
// ---------------------------------------------------------------------------
__global__ __launch_bounds__(256) void agg_kernel(
        const unsigned short* __restrict__ gbf, const unsigned short* __restrict__ Pt,
        const float* __restrict__ dinv, const float* __restrict__ bias,
        const float* __restrict__ x, float* __restrict__ out) {
    __shared__ __align__(16) unsigned short Al[128][64];
    __shared__ __align__(16) unsigned short Bl[128][64];
    int t = threadIdx.x;
    int w = t >> 6, ln = t & 63;
    int l0 = blockIdx.x * 128;            // l tile
    int n0 = blockIdx.y * 128;            // n' tile
    int wm = w >> 1, wn = w & 1;
    int lr = ln & 15, lg = ln >> 4;

    f32x4 acc[4][4] = {};

    for (int k0 = 0; k0 < LL; k0 += 64) {
        #pragma unroll
        for (int it = 0; it < 4; ++it) {
            int c = it * 256 + t;
            const unsigned short* g = gbf + (size_t)(l0 + (c >> 3)) * LL + k0 + (c & 7) * 8;
            unsigned short* lp = &Al[0][0] + (size_t)(it * 256 + w * 64) * 8;
            gload16(g, lp);
        }
        #pragma unroll
        for (int it = 0; it < 4; ++it) {
            int c = it * 256 + t;
            const unsigned short* g = Pt + (size_t)(n0 + (c >> 3)) * LL + k0 + (c & 7) * 8;
            unsigned short* lp = &Bl[0][0] + (size_t)(it * 256 + w * 64) * 8;
            gload16(g, lp);
        }
        __syncthreads();
        #pragma unroll
        for (int kk = 0; kk < 64; kk += 32) {
            bf16x8 af[4], bq[4];
            #pragma unroll
            for (int i = 0; i < 4; ++i)
                af[i] = *(const bf16x8*)&Al[wm * 64 + i * 16 + lr][kk + lg * 8];
            #pragma unroll
            for (int j = 0; j < 4; ++j)
                bq[j] = *(const bf16x8*)&Bl[wn * 64 + j * 16 + lr][kk + lg * 8];
            #pragma unroll
            for (int i = 0; i < 4; ++i)
                #pragma unroll
                for (int j = 0; j < 4; ++j)
                    acc[i][j] = __builtin_amdgcn_mfma_f32_16x16x32_bf16(
                        af[i], bq[j], acc[i][j], 0, 0, 0);
        }
        __syncthreads();
    }

    int b = n0 >> 8;
    #pragma unroll
    for (int j = 0; j < 4; ++j) {
        int np = n0 + wn * 64 + j * 16 + lr;     // n' column
        int o = np & (DD - 1);
        float bo = bias[o];
        #pragma unroll
        for (int i = 0; i < 4; ++i) {
            int lrow = l0 + wm * 64 + i * 16 + lg * 4;   // 4 consecutive l
            float4 dv = *(const float4*)(dinv + lrow);
            ushort4 pv = *(const ushort4*)(Pt + (size_t)np * LL + lrow);
            float dva[4] = {dv.x, dv.y, dv.z, dv.w};
            unsigned short pva[4] = {pv.x, pv.y, pv.z, pv.w};
            #pragma unroll
            for (int r = 0; r < 4; ++r) {
                float aggv = dva[r] * (acc[i][j][r] + bf2f(pva[r])) + bo;
                float rl = fmaxf(aggv, 0.0f);
                size_t oi = ((size_t)(b * LL + lrow + r)) * DD + o;
                out[oi] = rl + x[oi];
            }
        }
    }
}

// ---------------------------------------------------------------------------
extern "C" void kernel_launch(void* const* d_in, const int* in_sizes, int n_in,
                              void* d_out, int out_size, void* d_ws, size_t ws_size,
                              hipStream_t stream) {
    const float* x     = (const float*)d_in[0];   // [16,2048,256]
    const float* graph = (const float*)d_in[1];   // [1,2048,2048]
    const float* W     = (const float*)d_in[2];   // [256,256]
    const float* bias  = (const float*)d_in[3];   // [256]
    float* out = (float*)d_out;

    char* ws = (char*)d_ws;
    float*          dinv = (float*)ws;                                   // 8 KB
    unsigned short* gbf  = (unsigned short*)(ws + 8192);                 // 8 MB
    unsigned short* Wt   = (unsigned short*)(ws + 8192 + 8388608);       // 128 KB
    unsigned short* Pt   = (unsigned short*)(ws + 8192 + 8388608 + 131072); // 16 MB

    prep_graph<<<LL, 256, 0, stream>>>(graph, dinv, gbf);
    prep_w<<<DD, 256, 0, stream>>>(W, Wt);
    linear_kernel<<<dim3((NB * LL) / 128, DD / 128), 256, 0, stream>>>(x, Wt, dinv, Pt);
    agg_kernel<<<dim3(LL / 128, (NB * DD) / 128), 256, 0, stream>>>(gbf, Pt, dinv, bias, x, out);
}

// Round 2
// 76.546 us; speedup vs baseline: 1.1822x; 1.1822x over previous
//
#include <hip/hip_runtime.h>
#include <hip/hip_bf16.h>
#include <stdint.h>

#define LL 2048   // sequence length
#define NB 16     // batch
#define DD 256    // din = dout
#define NT 32     // K-tiles (2048/64) in agg

typedef __bf16 bf16x8 __attribute__((ext_vector_type(8)));
typedef float f32x4 __attribute__((ext_vector_type(4)));

__device__ __forceinline__ unsigned short f2bf(float f) {
    uint32_t u = __float_as_uint(f);
    u = (u + 0x7FFFu + ((u >> 16) & 1u)) >> 16;   // RNE
    return (unsigned short)u;
}

__device__ __forceinline__ float bf2f(unsigned short v) {
    return __uint_as_float(((uint32_t)v) << 16);
}

__device__ __forceinline__ void gload16(const void* g, void* l) {
    __builtin_amdgcn_global_load_lds(
        (const __attribute__((address_space(1))) void*)g,
        (__attribute__((address_space(3))) void*)l,
        16, 0, 0);
}

#define DSREAD(dst, off) asm volatile("ds_read_b128 %0, %1" : "=v"(dst) : "v"(off))

// ---------------------------------------------------------------------------
// Kernel 1: per-row degree -> dinv, plus graph f32 -> bf16 conversion.
// ---------------------------------------------------------------------------
__global__ __launch_bounds__(256) void prep_graph(
        const float* __restrict__ graph, float* __restrict__ dinv,
        unsigned short* __restrict__ gbf) {
    int r = blockIdx.x;
    int t = threadIdx.x;
    const float4* row = (const float4*)(graph + (size_t)r * LL);
    float4 v0 = row[t * 2 + 0];
    float4 v1 = row[t * 2 + 1];
    float s = v0.x + v0.y + v0.z + v0.w + v1.x + v1.y + v1.z + v1.w;

    unsigned short* gd = gbf + (size_t)r * LL + t * 8;
    *(ushort4*)(gd + 0) = make_ushort4(f2bf(v0.x), f2bf(v0.y), f2bf(v0.z), f2bf(v0.w));
    *(ushort4*)(gd + 4) = make_ushort4(f2bf(v1.x), f2bf(v1.y), f2bf(v1.z), f2bf(v1.w));

    #pragma unroll
    for (int off = 32; off > 0; off >>= 1) s += __shfl_down(s, off, 64);
    __shared__ float red[4];
    if ((t & 63) == 0) red[t >> 6] = s;
    __syncthreads();
    if (t == 0) {
        float deg = red[0] + red[1] + red[2] + red[3] + 1.0f;  // + self loop
        dinv[r] = 1.0f / sqrtf(deg);
    }
}

// ---------------------------------------------------------------------------
// Kernel 2: Wt[o][d] = bf16(W[d][o])
// ---------------------------------------------------------------------------
__global__ __launch_bounds__(256) void prep_w(
        const float* __restrict__ W, unsigned short* __restrict__ Wt) {
    int tid = blockIdx.x * 256 + threadIdx.x;
    int d = tid >> 8, o = tid & 255;
    Wt[o * DD + d] = f2bf(W[tid]);
}

// ---------------------------------------------------------------------------
// Kernel 3: Pt[b*256+o][m] = bf16( dinv[m] * sum_d x[b,m,d] * W[d,o] )
// (unchanged from R1 — passes, ~15us)
// ---------------------------------------------------------------------------
__global__ __launch_bounds__(256) void linear_kernel(
        const float* __restrict__ x, const unsigned short* __restrict__ Wt,
        const float* __restrict__ dinv, unsigned short* __restrict__ Pt) {
    __shared__ __align__(16) unsigned short Al[128][64];
    __shared__ __align__(16) unsigned short Bl[128][64];
    int t = threadIdx.x;
    int w = t >> 6, ln = t & 63;
    int m0 = blockIdx.x * 128;
    int n0 = blockIdx.y * 128;
    int b  = m0 >> 11;
    int ml0 = m0 & (LL - 1);
    int wm = w >> 1, wn = w & 1;
    int lr = ln & 15, lg = ln >> 4;

    f32x4 acc[4][4] = {};

    for (int k0 = 0; k0 < DD; k0 += 64) {
        #pragma unroll
        for (int it = 0; it < 8; ++it) {
            int c = it * 256 + t;
            int row = c >> 4, col = (c & 15) * 4;
            float4 v = *(const float4*)(x + (size_t)(m0 + row) * DD + k0 + col);
            *(ushort4*)(&Al[row][col]) =
                make_ushort4(f2bf(v.x), f2bf(v.y), f2bf(v.z), f2bf(v.w));
        }
        #pragma unroll
        for (int it = 0; it < 4; ++it) {
            int c = it * 256 + t;
            const unsigned short* g = Wt + (size_t)(n0 + (c >> 3)) * DD + k0 + (c & 7) * 8;
            unsigned short* lp = &Bl[0][0] + (size_t)(it * 256 + w * 64) * 8;
            gload16(g, lp);
        }
        __syncthreads();
        #pragma unroll
        for (int kk = 0; kk < 64; kk += 32) {
            bf16x8 af[4], bq[4];
            #pragma unroll
            for (int i = 0; i < 4; ++i)
                af[i] = *(const bf16x8*)&Al[wm * 64 + i * 16 + lr][kk + lg * 8];
            #pragma unroll
            for (int j = 0; j < 4; ++j)
                bq[j] = *(const bf16x8*)&Bl[wn * 64 + j * 16 + lr][kk + lg * 8];
            #pragma unroll
            for (int i = 0; i < 4; ++i)
                #pragma unroll
                for (int j = 0; j < 4; ++j)
                    acc[i][j] = __builtin_amdgcn_mfma_f32_16x16x32_bf16(
                        af[i], bq[j], acc[i][j], 0, 0, 0);
        }
        __syncthreads();
    }

    #pragma unroll
    for (int i = 0; i < 4; ++i) {
        int ml = ml0 + wm * 64 + i * 16 + lg * 4;
        float4 dv = *(const float4*)(dinv + ml);
        #pragma unroll
        for (int j = 0; j < 4; ++j) {
            int o = n0 + wn * 64 + j * 16 + lr;
            ushort4 pk = make_ushort4(f2bf(dv.x * acc[i][j][0]),
                                      f2bf(dv.y * acc[i][j][1]),
                                      f2bf(dv.z * acc[i][j][2]),
                                      f2bf(dv.w * acc[i][j][3]));
            *(ushort4*)(Pt + ((size_t)(b * DD + o)) * LL + ml) = pk;
        }
    }
}

// ---------------------------------------------------------------------------
// Kernel 4: agg = gbf @ Pt^T, phased schedule (T2 swizzle + T3/T4 counted
// vmcnt + T5 setprio). BM=128 (l), BN=256 (n'), BK=64, 8 waves (2Mx4N),
// 3-buffer LDS ring (144 KiB), 256 blocks = 1/CU.
// Epilogue: out = relu(dinv[l]*(S + Pt[n'][l]) + bias[o]) + x
// ---------------------------------------------------------------------------
__global__ __launch_bounds__(512, 2) void agg_kernel(
        const unsigned short* __restrict__ gbf, const unsigned short* __restrict__ Pt,
        const float* __restrict__ dinv, const float* __restrict__ bias,
        const float* __restrict__ x, float* __restrict__ out) {
    // per buffer: A 128x64 bf16 (16KB = 8192 ush) + B 256x64 (32KB = 16384 ush)
    __shared__ unsigned short lds[3 * 24576];   // 144 KiB

    const int t = threadIdx.x;
    const int w = t >> 6, ln = t & 63;
    const int wm = w >> 2, wn = w & 3;          // 2 x 4 wave grid
    const int lr = ln & 15, lg = ln >> 4;
    const int s7 = lr & 7;

    // XCD-aware bijective swizzle: 32 consecutive wgs per XCD = 2 l-tiles x 16 n'-tiles
    int bid = blockIdx.x;
    int wg = (bid & 7) * 32 + (bid >> 3);
    const int l0 = (wg >> 4) * 128;
    const int n0 = (wg & 15) * 256;

    // --- staging source pointers (pre-swizzled global: slot_src = slot_lin ^ (row&7)) ---
    const int rt = t >> 3;                       // row within 64-row unit
    const int st = (t & 7) ^ (rt & 7);           // swizzled source slot
    const unsigned short* a0 = gbf + (size_t)(l0 + rt) * LL + st * 8;
    const unsigned short* a1 = a0 + (size_t)64 * LL;
    const unsigned short* b0 = Pt + (size_t)(n0 + rt) * LL + st * 8;
    const unsigned short* b1 = b0 + (size_t)64 * LL;
    const unsigned short* b2 = b0 + (size_t)128 * LL;
    const unsigned short* b3 = b0 + (size_t)192 * LL;
    const int wd = w * 512;                      // wave-uniform LDS dst (ushort units)

    f32x4 acc[4][4] = {};

    // --- prologue: stage tiles 0,1 into bufs 0,1; wait tile 0 (counted) ---
    #pragma unroll
    for (int kt = 0; kt < 2; ++kt) {
        int sbp = kt * 24576, ko = kt * 64;
        gload16(a0 + ko, lds + sbp + wd);
        gload16(a1 + ko, lds + sbp + 4096 + wd);
        gload16(b0 + ko, lds + sbp + 8192 + wd);
        gload16(b1 + ko, lds + sbp + 12288 + wd);
        gload16(b2 + ko, lds + sbp + 16384 + wd);
        gload16(b3 + ko, lds + sbp + 20480 + wd);
    }
    asm volatile("s_waitcnt vmcnt(6)" ::: "memory");
    __builtin_amdgcn_s_barrier();

    int cur = 0;
    for (int it = 0; it < NT; ++it) {
        int stg = cur - 1; if (stg < 0) stg = 2;         // (cur+2)%3
        const int ktn = (it + 2 < NT) ? it + 2 : NT - 1; // clamp tail (dead buffer)
        const int cb = cur * 49152;                      // compute buf, bytes
        const int sb = stg * 24576;                      // stage buf, ushorts
        const int ko = ktn * 64;

        // ================= phase 0 =================
        bf16x8 bq[4][2], af[2][2];
        #pragma unroll
        for (int j = 0; j < 4; ++j)
            #pragma unroll
            for (int kk = 0; kk < 2; ++kk) {
                int off = cb + 16384 + (wn * 64 + j * 16 + lr) * 128
                        + (((kk * 4 + lg) ^ s7) << 4);
                DSREAD(bq[j][kk], off);
            }
        #pragma unroll
        for (int i = 0; i < 2; ++i)
            #pragma unroll
            for (int kk = 0; kk < 2; ++kk) {
                int off = cb + (wm * 64 + i * 16 + lr) * 128
                        + (((kk * 4 + lg) ^ s7) << 4);
                DSREAD(af[i][kk], off);
            }
        gload16(a0 + ko, lds + sb + wd);
        gload16(a1 + ko, lds + sb + 4096 + wd);
        gload16(b0 + ko, lds + sb + 8192 + wd);
        __builtin_amdgcn_s_barrier();
        asm volatile("s_waitcnt lgkmcnt(0)" ::: "memory");
        __builtin_amdgcn_sched_barrier(0);
        __builtin_amdgcn_s_setprio(1);
        #pragma unroll
        for (int i = 0; i < 2; ++i)
            #pragma unroll
            for (int j = 0; j < 4; ++j) {
                acc[i][j] = __builtin_amdgcn_mfma_f32_16x16x32_bf16(
                    af[i][0], bq[j][0], acc[i][j], 0, 0, 0);
                acc[i][j] = __builtin_amdgcn_mfma_f32_16x16x32_bf16(
                    af[i][1], bq[j][1], acc[i][j], 0, 0, 0);
            }
        __builtin_amdgcn_s_setprio(0);
        __builtin_amdgcn_sched_barrier(0);
        __builtin_amdgcn_s_barrier();

        // ================= phase 1 =================
        bf16x8 ag[2][2];
        #pragma unroll
        for (int i = 0; i < 2; ++i)
            #pragma unroll
            for (int kk = 0; kk < 2; ++kk) {
                int off = cb + (wm * 64 + (i + 2) * 16 + lr) * 128
                        + (((kk * 4 + lg) ^ s7) << 4);
                DSREAD(ag[i][kk], off);
            }
        gload16(b1 + ko, lds + sb + 12288 + wd);
        gload16(b2 + ko, lds + sb + 16384 + wd);
        gload16(b3 + ko, lds + sb + 20480 + wd);
        __builtin_amdgcn_s_barrier();
        asm volatile("s_waitcnt lgkmcnt(0)" ::: "memory");
        __builtin_amdgcn_sched_barrier(0);
        __builtin_amdgcn_s_setprio(1);
        #pragma unroll
        for (int i = 0; i < 2; ++i)
            #pragma unroll
            for (int j = 0; j < 4; ++j) {
                acc[i + 2][j] = __builtin_amdgcn_mfma_f32_16x16x32_bf16(
                    ag[i][0], bq[j][0], acc[i + 2][j], 0, 0, 0);
                acc[i + 2][j] = __builtin_amdgcn_mfma_f32_16x16x32_bf16(
                    ag[i][1], bq[j][1], acc[i + 2][j], 0, 0, 0);
            }
        __builtin_amdgcn_s_setprio(0);
        __builtin_amdgcn_sched_barrier(0);
        asm volatile("s_waitcnt vmcnt(6)" ::: "memory");   // counted, never 0
        __builtin_amdgcn_s_barrier();

        cur = (cur == 2) ? 0 : cur + 1;
    }

    // ================= epilogue =================
    const int b = n0 >> 8;
    #pragma unroll
    for (int j = 0; j < 4; ++j) {
        int np = n0 + wn * 64 + j * 16 + lr;
        int o = np & (DD - 1);
        float bo = bias[o];
        #pragma unroll
        for (int i = 0; i < 4; ++i) {
            int lrow = l0 + wm * 64 + i * 16 + lg * 4;
            float4 dv = *(const float4*)(dinv + lrow);
            ushort4 pv = *(const ushort4*)(Pt + (size_t)np * LL + lrow);
            float dva[4] = {dv.x, dv.y, dv.z, dv.w};
            unsigned short pva[4] = {pv.x, pv.y, pv.z, pv.w};
            #pragma unroll
            for (int r = 0; r < 4; ++r) {
                float aggv = dva[r] * (acc[i][j][r] + bf2f(pva[r])) + bo;
                float rl = fmaxf(aggv, 0.0f);
                size_t oi = ((size_t)(b * LL + lrow + r)) * DD + o;
                out[oi] = rl + x[oi];
            }
        }
    }
}

// ---------------------------------------------------------------------------
extern "C" void kernel_launch(void* const* d_in, const int* in_sizes, int n_in,
                              void* d_out, int out_size, void* d_ws, size_t ws_size,
                              hipStream_t stream) {
    const float* x     = (const float*)d_in[0];   // [16,2048,256]
    const float* graph = (const float*)d_in[1];   // [1,2048,2048]
    const float* W     = (const float*)d_in[2];   // [256,256]
    const float* bias  = (const float*)d_in[3];   // [256]
    float* out = (float*)d_out;

    char* ws = (char*)d_ws;
    float*          dinv = (float*)ws;                                      // 8 KB
    unsigned short* gbf  = (unsigned short*)(ws + 8192);                    // 8 MB
    unsigned short* Wt   = (unsigned short*)(ws + 8192 + 8388608);          // 128 KB
    unsigned short* Pt   = (unsigned short*)(ws + 8192 + 8388608 + 131072); // 16 MB

    prep_graph<<<LL, 256, 0, stream>>>(graph, dinv, gbf);
    prep_w<<<DD, 256, 0, stream>>>(W, Wt);
    linear_kernel<<<dim3((NB * LL) / 128, DD / 128), 256, 0, stream>>>(x, Wt, dinv, Pt);
    agg_kernel<<<256, 512, 0, stream>>>(gbf, Pt, dinv, bias, x, out);
}

// Round 3
// 63.355 us; speedup vs baseline: 1.4283x; 1.2082x over previous
//
#include <hip/hip_runtime.h>
#include <hip/hip_bf16.h>
#include <stdint.h>

#define LL 2048   // sequence length
#define NB 16     // batch
#define DD 256    // din = dout
#define NT2 16    // K-tiles (2048/128) in agg

typedef __bf16 bf16x8 __attribute__((ext_vector_type(8)));
typedef float f32x4 __attribute__((ext_vector_type(4)));
typedef int i32x4 __attribute__((ext_vector_type(4)));
typedef int i32x8 __attribute__((ext_vector_type(8)));
union Frag8 { i32x8 v8; i32x4 v4[2]; };

__device__ __forceinline__ unsigned short f2bf(float f) {
    uint32_t u = __float_as_uint(f);
    u = (u + 0x7FFFu + ((u >> 16) & 1u)) >> 16;   // RNE
    return (unsigned short)u;
}

__device__ __forceinline__ float bf2f(unsigned short v) {
    return __uint_as_float(((uint32_t)v) << 16);
}

// ---- fp8 e4m3fn helpers -----------------------------------------------------
#if __has_builtin(__builtin_amdgcn_cvt_pk_fp8_f32)
__device__ __forceinline__ uint32_t pk4fp8(float a, float b, float c, float d) {
    int r = 0;
    r = __builtin_amdgcn_cvt_pk_fp8_f32(a, b, r, false);
    r = __builtin_amdgcn_cvt_pk_fp8_f32(c, d, r, true);
    return (uint32_t)r;
}
#else
__device__ __forceinline__ uint32_t f2fp8_1(float f) {
    uint32_t u = __float_as_uint(f);
    uint32_t s = (u >> 24) & 0x80u;
    uint32_t au = u & 0x7FFFFFFFu;
    float af = __uint_as_float(au);
    if (af >= 448.0f) return s | 0x7Eu;
    if (af < 0x1p-6f) {
        uint32_t q = (uint32_t)rintf(af * 512.0f);   // subnormal units 2^-9
        return s | q;
    }
    uint32_t r = au + (0x7FFFFu + ((au >> 20) & 1u));  // RNE to 3 mantissa bits
    uint32_t e8 = (r >> 23) - 120u;
    return s | (e8 << 3) | ((r >> 20) & 7u);
}
__device__ __forceinline__ uint32_t pk4fp8(float a, float b, float c, float d) {
    return f2fp8_1(a) | (f2fp8_1(b) << 8) | (f2fp8_1(c) << 16) | (f2fp8_1(d) << 24);
}
#endif

__device__ __forceinline__ float fp8tof(uint32_t b) {
    uint32_t s = (b & 0x80u) << 24;
    uint32_t e = (b >> 3) & 15u, m = b & 7u;
    float v = (e == 0) ? (float)m * 0x1p-9f
            : __uint_as_float(((e + 120u) << 23) | (m << 20));
    return __uint_as_float(__float_as_uint(v) | s);
}

__device__ __forceinline__ void gload16(const void* g, void* l) {
    __builtin_amdgcn_global_load_lds(
        (const __attribute__((address_space(1))) void*)g,
        (__attribute__((address_space(3))) void*)l,
        16, 0, 0);
}

#define DSREAD(dst, off) asm volatile("ds_read_b128 %0, %1" : "=v"(dst) : "v"(off))

// ---------------------------------------------------------------------------
// Kernel 1: degree -> dinv, plus graph f32 -> fp8 e4m3 (values are exactly 0/1)
// ---------------------------------------------------------------------------
__global__ __launch_bounds__(256) void prep_graph(
        const float* __restrict__ graph, float* __restrict__ dinv,
        uint8_t* __restrict__ gq) {
    int r = blockIdx.x;
    int t = threadIdx.x;
    const float4* row = (const float4*)(graph + (size_t)r * LL);
    float4 v0 = row[t * 2 + 0];
    float4 v1 = row[t * 2 + 1];
    float s = v0.x + v0.y + v0.z + v0.w + v1.x + v1.y + v1.z + v1.w;

    uint32_t lo = (v0.x != 0.f ? 0x38u : 0u) | ((v0.y != 0.f ? 0x38u : 0u) << 8)
                | ((v0.z != 0.f ? 0x38u : 0u) << 16) | ((v0.w != 0.f ? 0x38u : 0u) << 24);
    uint32_t hi = (v1.x != 0.f ? 0x38u : 0u) | ((v1.y != 0.f ? 0x38u : 0u) << 8)
                | ((v1.z != 0.f ? 0x38u : 0u) << 16) | ((v1.w != 0.f ? 0x38u : 0u) << 24);
    *(uint2*)(gq + (size_t)r * LL + t * 8) = make_uint2(lo, hi);

    #pragma unroll
    for (int off = 32; off > 0; off >>= 1) s += __shfl_down(s, off, 64);
    __shared__ float red[4];
    if ((t & 63) == 0) red[t >> 6] = s;
    __syncthreads();
    if (t == 0) {
        float deg = red[0] + red[1] + red[2] + red[3] + 1.0f;  // + self loop
        dinv[r] = 1.0f / sqrtf(deg);
    }
}

// ---------------------------------------------------------------------------
// Kernel 2: Wt[o][d] = bf16(W[d][o])
// ---------------------------------------------------------------------------
__global__ __launch_bounds__(256) void prep_w(
        const float* __restrict__ W, unsigned short* __restrict__ Wt) {
    int tid = blockIdx.x * 256 + threadIdx.x;
    int d = tid >> 8, o = tid & 255;
    Wt[o * DD + d] = f2bf(W[tid]);
}

// ---------------------------------------------------------------------------
// Kernel 3: Pq[b*256+o][m] = fp8( dinv[m] * sum_d x[b,m,d] * W[d,o] )
// ---------------------------------------------------------------------------
__global__ __launch_bounds__(256) void linear_kernel(
        const float* __restrict__ x, const unsigned short* __restrict__ Wt,
        const float* __restrict__ dinv, uint8_t* __restrict__ Pq) {
    __shared__ __align__(16) unsigned short Al[128][64];
    __shared__ __align__(16) unsigned short Bl[128][64];
    int t = threadIdx.x;
    int w = t >> 6, ln = t & 63;
    int m0 = blockIdx.x * 128;
    int n0 = blockIdx.y * 128;
    int b  = m0 >> 11;
    int ml0 = m0 & (LL - 1);
    int wm = w >> 1, wn = w & 1;
    int lr = ln & 15, lg = ln >> 4;

    f32x4 acc[4][4] = {};

    for (int k0 = 0; k0 < DD; k0 += 64) {
        #pragma unroll
        for (int it = 0; it < 8; ++it) {
            int c = it * 256 + t;
            int row = c >> 4, col = (c & 15) * 4;
            float4 v = *(const float4*)(x + (size_t)(m0 + row) * DD + k0 + col);
            *(ushort4*)(&Al[row][col]) =
                make_ushort4(f2bf(v.x), f2bf(v.y), f2bf(v.z), f2bf(v.w));
        }
        #pragma unroll
        for (int it = 0; it < 4; ++it) {
            int c = it * 256 + t;
            const unsigned short* g = Wt + (size_t)(n0 + (c >> 3)) * DD + k0 + (c & 7) * 8;
            unsigned short* lp = &Bl[0][0] + (size_t)(it * 256 + w * 64) * 8;
            gload16(g, lp);
        }
        __syncthreads();
        #pragma unroll
        for (int kk = 0; kk < 64; kk += 32) {
            bf16x8 af[4], bq[4];
            #pragma unroll
            for (int i = 0; i < 4; ++i)
                af[i] = *(const bf16x8*)&Al[wm * 64 + i * 16 + lr][kk + lg * 8];
            #pragma unroll
            for (int j = 0; j < 4; ++j)
                bq[j] = *(const bf16x8*)&Bl[wn * 64 + j * 16 + lr][kk + lg * 8];
            #pragma unroll
            for (int i = 0; i < 4; ++i)
                #pragma unroll
                for (int j = 0; j < 4; ++j)
                    acc[i][j] = __builtin_amdgcn_mfma_f32_16x16x32_bf16(
                        af[i], bq[j], acc[i][j], 0, 0, 0);
        }
        __syncthreads();
    }

    #pragma unroll
    for (int i = 0; i < 4; ++i) {
        int ml = ml0 + wm * 64 + i * 16 + lg * 4;
        float4 dv = *(const float4*)(dinv + ml);
        #pragma unroll
        for (int j = 0; j < 4; ++j) {
            int o = n0 + wn * 64 + j * 16 + lr;
            uint32_t pk = pk4fp8(dv.x * acc[i][j][0], dv.y * acc[i][j][1],
                                 dv.z * acc[i][j][2], dv.w * acc[i][j][3]);
            *(uint32_t*)(Pq + ((size_t)(b * DD + o)) * LL + ml) = pk;
        }
    }
}

// ---------------------------------------------------------------------------
// Kernel 4: agg = gq @ Pq^T in MX-fp8 (scale=1.0). BM=128 (l), BN=256 (n'),
// BK=128 k-bytes, 8 waves (2Mx4N), 3-buffer LDS ring, T2 swizzle, counted
// vmcnt, setprio. XCD partition: 2 n'-tiles x 16 l-tiles per XCD so B panels
// (2x512KB fp8) are L2-resident; gq (4MB) shared via L3.
// Epilogue: out = relu(dinv[l]*(S + Pq[n'][l]) + bias[o]) + x
// ---------------------------------------------------------------------------
__global__ __launch_bounds__(512, 2) void agg_kernel(
        const uint8_t* __restrict__ gq, const uint8_t* __restrict__ Pq,
        const float* __restrict__ dinv, const float* __restrict__ bias,
        const float* __restrict__ x, float* __restrict__ out) {
    // per buffer: A 128x128B (16KB) + B 256x128B (32KB)
    __shared__ unsigned char lds[3 * 49152];   // 144 KiB

    const int t = threadIdx.x;
    const int w = t >> 6, ln = t & 63;
    const int wm = w >> 2, wn = w & 3;          // 2 x 4 wave grid
    const int lr = ln & 15, lg = ln >> 4;
    const int s7 = lr & 7;

    int bid = blockIdx.x;
    int wg = (bid & 7) * 32 + (bid >> 3);
    const int l0 = (wg & 15) * 128;             // 16 l-tiles per XCD
    const int n0 = (wg >> 4) * 256;             // 2 n'-tiles per XCD (L2-resident B)

    // staging source (pre-swizzled global: slot_src = slot_lin ^ (row&7))
    const int rt = t >> 3;
    const int st = (t & 7) ^ (rt & 7);
    const uint8_t* a0 = gq + (size_t)(l0 + rt) * LL + st * 16;
    const uint8_t* a1 = a0 + (size_t)64 * LL;
    const uint8_t* b0 = Pq + (size_t)(n0 + rt) * LL + st * 16;
    const uint8_t* b1 = b0 + (size_t)64 * LL;
    const uint8_t* b2 = b0 + (size_t)128 * LL;
    const uint8_t* b3 = b0 + (size_t)192 * LL;
    const int wd = w * 1024;                    // wave-uniform LDS dst (bytes)

    f32x4 acc[4][4] = {};

    // prologue: stage K-tiles 0,1 into bufs 0,1
    #pragma unroll
    for (int kt = 0; kt < 2; ++kt) {
        int sbp = kt * 49152, ko = kt * 128;
        gload16(a0 + ko, lds + sbp + wd);
        gload16(a1 + ko, lds + sbp + 8192 + wd);
        gload16(b0 + ko, lds + sbp + 16384 + wd);
        gload16(b1 + ko, lds + sbp + 24576 + wd);
        gload16(b2 + ko, lds + sbp + 32768 + wd);
        gload16(b3 + ko, lds + sbp + 40960 + wd);
    }
    asm volatile("s_waitcnt vmcnt(6)" ::: "memory");
    __builtin_amdgcn_s_barrier();

    int cur = 0;
    for (int it = 0; it < NT2; ++it) {
        int stg = cur - 1; if (stg < 0) stg = 2;           // (cur+2)%3
        const int ktn = (it + 2 < NT2) ? it + 2 : NT2 - 1; // clamp tail
        const int cb = cur * 49152;
        const int sb = stg * 49152;
        const int ko = ktn * 128;

        // ================= phase 0 =================
        Frag8 fb[4], fa[2];
        #pragma unroll
        for (int j = 0; j < 4; ++j)
            #pragma unroll
            for (int h = 0; h < 2; ++h) {
                int off = cb + 16384 + (wn * 64 + j * 16 + lr) * 128
                        + (((lg * 2 + h) ^ s7) << 4);
                DSREAD(fb[j].v4[h], off);
            }
        #pragma unroll
        for (int i = 0; i < 2; ++i)
            #pragma unroll
            for (int h = 0; h < 2; ++h) {
                int off = cb + (wm * 64 + i * 16 + lr) * 128
                        + (((lg * 2 + h) ^ s7) << 4);
                DSREAD(fa[i].v4[h], off);
            }
        gload16(a0 + ko, lds + sb + wd);
        gload16(a1 + ko, lds + sb + 8192 + wd);
        gload16(b0 + ko, lds + sb + 16384 + wd);
        __builtin_amdgcn_s_barrier();
        asm volatile("s_waitcnt lgkmcnt(0)" ::: "memory");
        __builtin_amdgcn_sched_barrier(0);
        __builtin_amdgcn_s_setprio(1);
        #pragma unroll
        for (int i = 0; i < 2; ++i)
            #pragma unroll
            for (int j = 0; j < 4; ++j)
                acc[i][j] = __builtin_amdgcn_mfma_scale_f32_16x16x128_f8f6f4(
                    fa[i].v8, fb[j].v8, acc[i][j], 0, 0, 0, 127, 0, 127);
        __builtin_amdgcn_s_setprio(0);
        __builtin_amdgcn_sched_barrier(0);
        __builtin_amdgcn_s_barrier();

        // ================= phase 1 =================
        Frag8 fc[2];
        #pragma unroll
        for (int i = 0; i < 2; ++i)
            #pragma unroll
            for (int h = 0; h < 2; ++h) {
                int off = cb + (wm * 64 + (i + 2) * 16 + lr) * 128
                        + (((lg * 2 + h) ^ s7) << 4);
                DSREAD(fc[i].v4[h], off);
            }
        gload16(b1 + ko, lds + sb + 24576 + wd);
        gload16(b2 + ko, lds + sb + 32768 + wd);
        gload16(b3 + ko, lds + sb + 40960 + wd);
        __builtin_amdgcn_s_barrier();
        asm volatile("s_waitcnt lgkmcnt(0)" ::: "memory");
        __builtin_amdgcn_sched_barrier(0);
        __builtin_amdgcn_s_setprio(1);
        #pragma unroll
        for (int i = 0; i < 2; ++i)
            #pragma unroll
            for (int j = 0; j < 4; ++j)
                acc[i + 2][j] = __builtin_amdgcn_mfma_scale_f32_16x16x128_f8f6f4(
                    fc[i].v8, fb[j].v8, acc[i + 2][j], 0, 0, 0, 127, 0, 127);
        __builtin_amdgcn_s_setprio(0);
        __builtin_amdgcn_sched_barrier(0);
        asm volatile("s_waitcnt vmcnt(6)" ::: "memory");   // counted, never 0
        __builtin_amdgcn_s_barrier();

        cur = (cur == 2) ? 0 : cur + 1;
    }

    // ================= epilogue =================
    const int b = n0 >> 8;
    #pragma unroll
    for (int j = 0; j < 4; ++j) {
        int np = n0 + wn * 64 + j * 16 + lr;
        int o = np & (DD - 1);
        float bo = bias[o];
        #pragma unroll
        for (int i = 0; i < 4; ++i) {
            int lrow = l0 + wm * 64 + i * 16 + lg * 4;
            float4 dv = *(const float4*)(dinv + lrow);
            uchar4 pv = *(const uchar4*)(Pq + (size_t)np * LL + lrow);
            float dva[4] = {dv.x, dv.y, dv.z, dv.w};
            float pva[4] = {fp8tof(pv.x), fp8tof(pv.y), fp8tof(pv.z), fp8tof(pv.w)};
            #pragma unroll
            for (int r = 0; r < 4; ++r) {
                float aggv = dva[r] * (acc[i][j][r] + pva[r]) + bo;
                float rl = fmaxf(aggv, 0.0f);
                size_t oi = ((size_t)(b * LL + lrow + r)) * DD + o;
                out[oi] = rl + x[oi];
            }
        }
    }
}

// ---------------------------------------------------------------------------
extern "C" void kernel_launch(void* const* d_in, const int* in_sizes, int n_in,
                              void* d_out, int out_size, void* d_ws, size_t ws_size,
                              hipStream_t stream) {
    const float* x     = (const float*)d_in[0];   // [16,2048,256]
    const float* graph = (const float*)d_in[1];   // [1,2048,2048]
    const float* W     = (const float*)d_in[2];   // [256,256]
    const float* bias  = (const float*)d_in[3];   // [256]
    float* out = (float*)d_out;

    char* ws = (char*)d_ws;
    float*          dinv = (float*)ws;                                   // 8 KB
    uint8_t*        gq   = (uint8_t*)(ws + 8192);                        // 4 MB
    unsigned short* Wt   = (unsigned short*)(ws + 8192 + 4194304);       // 128 KB
    uint8_t*        Pq   = (uint8_t*)(ws + 8192 + 4194304 + 131072);     // 8 MB

    prep_graph<<<LL, 256, 0, stream>>>(graph, dinv, gq);
    prep_w<<<DD, 256, 0, stream>>>(W, Wt);
    linear_kernel<<<dim3((NB * LL) / 128, DD / 128), 256, 0, stream>>>(x, Wt, dinv, Pq);
    agg_kernel<<<256, 512, 0, stream>>>(gq, Pq, dinv, bias, x, out);
}

// Round 4
// 57.665 us; speedup vs baseline: 1.5692x; 1.0987x over previous
//
#include <hip/hip_runtime.h>
#include <hip/hip_bf16.h>
#include <stdint.h>

#define LL 2048   // sequence length
#define NB 16     // batch
#define DD 256    // din = dout
#define NT2 16    // K-tiles (2048/128) in agg

typedef __bf16 bf16x8 __attribute__((ext_vector_type(8)));
typedef float f32x4 __attribute__((ext_vector_type(4)));
typedef int i32x4 __attribute__((ext_vector_type(4)));
typedef int i32x8 __attribute__((ext_vector_type(8)));
union Frag8 { i32x8 v8; i32x4 v4[2]; };

__device__ __forceinline__ unsigned short f2bf(float f) {
    __hip_bfloat16 h = __float2bfloat16(f);   // RNE; compiler lowers to v_cvt
    return *reinterpret_cast<unsigned short*>(&h);
}

__device__ __forceinline__ float bf2f(unsigned short v) {
    return __uint_as_float(((uint32_t)v) << 16);
}

// ---- fp8 e4m3fn helpers -----------------------------------------------------
#if __has_builtin(__builtin_amdgcn_cvt_pk_fp8_f32)
__device__ __forceinline__ uint32_t pk4fp8(float a, float b, float c, float d) {
    int r = 0;
    r = __builtin_amdgcn_cvt_pk_fp8_f32(a, b, r, false);
    r = __builtin_amdgcn_cvt_pk_fp8_f32(c, d, r, true);
    return (uint32_t)r;
}
#else
__device__ __forceinline__ uint32_t f2fp8_1(float f) {
    uint32_t u = __float_as_uint(f);
    uint32_t s = (u >> 24) & 0x80u;
    uint32_t au = u & 0x7FFFFFFFu;
    float af = __uint_as_float(au);
    if (af >= 448.0f) return s | 0x7Eu;
    if (af < 0x1p-6f) {
        uint32_t q = (uint32_t)rintf(af * 512.0f);
        return s | q;
    }
    uint32_t r = au + (0x7FFFFu + ((au >> 20) & 1u));
    uint32_t e8 = (r >> 23) - 120u;
    return s | (e8 << 3) | ((r >> 20) & 7u);
}
__device__ __forceinline__ uint32_t pk4fp8(float a, float b, float c, float d) {
    return f2fp8_1(a) | (f2fp8_1(b) << 8) | (f2fp8_1(c) << 16) | (f2fp8_1(d) << 24);
}
#endif

__device__ __forceinline__ float fp8tof(uint32_t b) {
    uint32_t s = (b & 0x80u) << 24;
    uint32_t e = (b >> 3) & 15u, m = b & 7u;
    float v = (e == 0) ? (float)m * 0x1p-9f
            : __uint_as_float(((e + 120u) << 23) | (m << 20));
    return __uint_as_float(__float_as_uint(v) | s);
}

__device__ __forceinline__ void gload16(const void* g, void* l) {
    __builtin_amdgcn_global_load_lds(
        (const __attribute__((address_space(1))) void*)g,
        (__attribute__((address_space(3))) void*)l,
        16, 0, 0);
}

#define DSREAD(dst, off) asm volatile("ds_read_b128 %0, %1" : "=v"(dst) : "v"(off))

// ---------------------------------------------------------------------------
// Kernel 1: degree -> dinv, plus graph f32 -> fp8 e4m3 (values exactly 0/1)
// ---------------------------------------------------------------------------
__global__ __launch_bounds__(256) void prep_graph(
        const float* __restrict__ graph, float* __restrict__ dinv,
        uint8_t* __restrict__ gq) {
    int r = blockIdx.x;
    int t = threadIdx.x;
    const float4* row = (const float4*)(graph + (size_t)r * LL);
    float4 v0 = row[t * 2 + 0];
    float4 v1 = row[t * 2 + 1];
    float s = v0.x + v0.y + v0.z + v0.w + v1.x + v1.y + v1.z + v1.w;

    uint32_t lo = (v0.x != 0.f ? 0x38u : 0u) | ((v0.y != 0.f ? 0x38u : 0u) << 8)
                | ((v0.z != 0.f ? 0x38u : 0u) << 16) | ((v0.w != 0.f ? 0x38u : 0u) << 24);
    uint32_t hi = (v1.x != 0.f ? 0x38u : 0u) | ((v1.y != 0.f ? 0x38u : 0u) << 8)
                | ((v1.z != 0.f ? 0x38u : 0u) << 16) | ((v1.w != 0.f ? 0x38u : 0u) << 24);
    *(uint2*)(gq + (size_t)r * LL + t * 8) = make_uint2(lo, hi);

    #pragma unroll
    for (int off = 32; off > 0; off >>= 1) s += __shfl_down(s, off, 64);
    __shared__ float red[4];
    if ((t & 63) == 0) red[t >> 6] = s;
    __syncthreads();
    if (t == 0) {
        float deg = red[0] + red[1] + red[2] + red[3] + 1.0f;  // + self loop
        dinv[r] = 1.0f / sqrtf(deg);
    }
}

// ---------------------------------------------------------------------------
// Kernel 2: Wt[o][d] = bf16(W[d][o])
// ---------------------------------------------------------------------------
__global__ __launch_bounds__(256) void prep_w(
        const float* __restrict__ W, unsigned short* __restrict__ Wt) {
    int tid = blockIdx.x * 256 + threadIdx.x;
    int d = tid >> 8, o = tid & 255;
    Wt[o * DD + d] = f2bf(W[tid]);
}

// ---------------------------------------------------------------------------
// Kernel 3: Pq[b*256+o][m] = fp8( dinv[m] * sum_d x[b,m,d] * W[d,o] )
// ---------------------------------------------------------------------------
__global__ __launch_bounds__(256) void linear_kernel(
        const float* __restrict__ x, const unsigned short* __restrict__ Wt,
        const float* __restrict__ dinv, uint8_t* __restrict__ Pq) {
    __shared__ __align__(16) unsigned short Al[128][64];
    __shared__ __align__(16) unsigned short Bl[128][64];
    int t = threadIdx.x;
    int w = t >> 6, ln = t & 63;
    int m0 = blockIdx.x * 128;
    int n0 = blockIdx.y * 128;
    int b  = m0 >> 11;
    int ml0 = m0 & (LL - 1);
    int wm = w >> 1, wn = w & 1;
    int lr = ln & 15, lg = ln >> 4;

    f32x4 acc[4][4] = {};

    for (int k0 = 0; k0 < DD; k0 += 64) {
        #pragma unroll
        for (int it = 0; it < 8; ++it) {
            int c = it * 256 + t;
            int row = c >> 4, col = (c & 15) * 4;
            float4 v = *(const float4*)(x + (size_t)(m0 + row) * DD + k0 + col);
            *(ushort4*)(&Al[row][col]) =
                make_ushort4(f2bf(v.x), f2bf(v.y), f2bf(v.z), f2bf(v.w));
        }
        #pragma unroll
        for (int it = 0; it < 4; ++it) {
            int c = it * 256 + t;
            const unsigned short* g = Wt + (size_t)(n0 + (c >> 3)) * DD + k0 + (c & 7) * 8;
            unsigned short* lp = &Bl[0][0] + (size_t)(it * 256 + w * 64) * 8;
            gload16(g, lp);
        }
        __syncthreads();
        #pragma unroll
        for (int kk = 0; kk < 64; kk += 32) {
            bf16x8 af[4], bq[4];
            #pragma unroll
            for (int i = 0; i < 4; ++i)
                af[i] = *(const bf16x8*)&Al[wm * 64 + i * 16 + lr][kk + lg * 8];
            #pragma unroll
            for (int j = 0; j < 4; ++j)
                bq[j] = *(const bf16x8*)&Bl[wn * 64 + j * 16 + lr][kk + lg * 8];
            #pragma unroll
            for (int i = 0; i < 4; ++i)
                #pragma unroll
                for (int j = 0; j < 4; ++j)
                    acc[i][j] = __builtin_amdgcn_mfma_f32_16x16x32_bf16(
                        af[i], bq[j], acc[i][j], 0, 0, 0);
        }
        __syncthreads();
    }

    #pragma unroll
    for (int i = 0; i < 4; ++i) {
        int ml = ml0 + wm * 64 + i * 16 + lg * 4;
        float4 dv = *(const float4*)(dinv + ml);
        #pragma unroll
        for (int j = 0; j < 4; ++j) {
            int o = n0 + wn * 64 + j * 16 + lr;
            uint32_t pk = pk4fp8(dv.x * acc[i][j][0], dv.y * acc[i][j][1],
                                 dv.z * acc[i][j][2], dv.w * acc[i][j][3]);
            *(uint32_t*)(Pq + ((size_t)(b * DD + o)) * LL + ml) = pk;
        }
    }
}

// ---------------------------------------------------------------------------
// Kernel 4: agg = gq @ Pq^T in MX-fp8 (scale=1.0).
// BM=BN=128, BK=128B, 4 waves (2x2, per-wave 64x64), 256 thr, double-buffered
// 64KB LDS -> 512 blocks = 2 blocks/CU (two INDEPENDENT barrier domains per CU
// hide each other's barrier/vmcnt drain). T2 swizzle, setprio, XCD partition:
// 4 n'-tiles x 16 l-tiles per XCD (B 1MB L2-resident, A via L2/L3).
// Epilogue: out = relu(dinv[l]*(S + Pq[n'][l]) + bias[o]) + x
// ---------------------------------------------------------------------------
__global__ __launch_bounds__(256, 2) void agg_kernel(
        const uint8_t* __restrict__ gq, const uint8_t* __restrict__ Pq,
        const float* __restrict__ dinv, const float* __restrict__ bias,
        const float* __restrict__ x, float* __restrict__ out) {
    // per buffer: A 128x128B (16KB) + B 128x128B (16KB); x2 buffers = 64 KiB
    __shared__ unsigned char lds[2 * 32768];

    const int t = threadIdx.x;
    const int w = t >> 6, ln = t & 63;
    const int wm = w >> 1, wn = w & 1;          // 2x2 wave grid
    const int lr = ln & 15, lg = ln >> 4;
    const int s7 = lr & 7;

    int bid = blockIdx.x;
    int wg = (bid & 7) * 64 + (bid >> 3);       // 64 contiguous wgs per XCD
    const int l0 = (wg & 15) * 128;             // 16 l-tiles per XCD
    const int n0 = (wg >> 4) * 128;             // 4 n'-tiles per XCD

    // staging source (pre-swizzled global: slot_src = slot_lin ^ (row&7))
    const int rt8 = t >> 3;                     // 0..31 (row within 32-row round)
    const int st = (t & 7) ^ (rt8 & 7);
    const uint8_t* ag = gq + (size_t)(l0 + rt8) * LL + st * 16;
    const uint8_t* bg = Pq + (size_t)(n0 + rt8) * LL + st * 16;
    const int wd = w * 1024;                    // wave-uniform LDS dst (bytes)

    f32x4 acc[4][4] = {};

    // prologue: stage K-tile 0 into buf 0
    #pragma unroll
    for (int r = 0; r < 4; ++r) {
        gload16(ag + (size_t)(32 * r) * LL, lds + r * 4096 + wd);
        gload16(bg + (size_t)(32 * r) * LL, lds + 16384 + r * 4096 + wd);
    }
    asm volatile("s_waitcnt vmcnt(0)" ::: "memory");
    __builtin_amdgcn_s_barrier();

    for (int it = 0; it < NT2; ++it) {
        const int cb = (it & 1) * 32768;        // compute buffer
        const int sb = cb ^ 32768;              // stage buffer

        // issue next tile's loads first (they complete under this iter's work)
        if (it + 1 < NT2) {
            const int ko = (it + 1) * 128;
            #pragma unroll
            for (int r = 0; r < 4; ++r) {
                gload16(ag + (size_t)(32 * r) * LL + ko, lds + sb + r * 4096 + wd);
                gload16(bg + (size_t)(32 * r) * LL + ko, lds + sb + 16384 + r * 4096 + wd);
            }
        }

        Frag8 fa[4], fb[4];
        #pragma unroll
        for (int i = 0; i < 4; ++i)
            #pragma unroll
            for (int h = 0; h < 2; ++h) {
                int off = cb + (wm * 64 + i * 16 + lr) * 128
                        + (((lg * 2 + h) ^ s7) << 4);
                DSREAD(fa[i].v4[h], off);
            }
        #pragma unroll
        for (int j = 0; j < 4; ++j)
            #pragma unroll
            for (int h = 0; h < 2; ++h) {
                int off = cb + 16384 + (wn * 64 + j * 16 + lr) * 128
                        + (((lg * 2 + h) ^ s7) << 4);
                DSREAD(fb[j].v4[h], off);
            }
        asm volatile("s_waitcnt lgkmcnt(0)" ::: "memory");
        __builtin_amdgcn_sched_barrier(0);
        __builtin_amdgcn_s_setprio(1);
        #pragma unroll
        for (int i = 0; i < 4; ++i)
            #pragma unroll
            for (int j = 0; j < 4; ++j)
                acc[i][j] = __builtin_amdgcn_mfma_scale_f32_16x16x128_f8f6f4(
                    fa[i].v8, fb[j].v8, acc[i][j], 0, 0, 0, 127, 0, 127);
        __builtin_amdgcn_s_setprio(0);
        __builtin_amdgcn_sched_barrier(0);
        asm volatile("s_waitcnt vmcnt(0)" ::: "memory");  // next buffer staged
        __builtin_amdgcn_s_barrier();
    }

    // ================= epilogue =================
    const int b = n0 >> 8;
    #pragma unroll
    for (int j = 0; j < 4; ++j) {
        int np = n0 + wn * 64 + j * 16 + lr;
        int o = np & (DD - 1);
        float bo = bias[o];
        #pragma unroll
        for (int i = 0; i < 4; ++i) {
            int lrow = l0 + wm * 64 + i * 16 + lg * 4;
            float4 dv = *(const float4*)(dinv + lrow);
            uchar4 pv = *(const uchar4*)(Pq + (size_t)np * LL + lrow);
            float dva[4] = {dv.x, dv.y, dv.z, dv.w};
            float pva[4] = {fp8tof(pv.x), fp8tof(pv.y), fp8tof(pv.z), fp8tof(pv.w)};
            #pragma unroll
            for (int r = 0; r < 4; ++r) {
                float aggv = dva[r] * (acc[i][j][r] + pva[r]) + bo;
                float rl = fmaxf(aggv, 0.0f);
                size_t oi = ((size_t)(b * LL + lrow + r)) * DD + o;
                out[oi] = rl + x[oi];
            }
        }
    }
}

// ---------------------------------------------------------------------------
extern "C" void kernel_launch(void* const* d_in, const int* in_sizes, int n_in,
                              void* d_out, int out_size, void* d_ws, size_t ws_size,
                              hipStream_t stream) {
    const float* x     = (const float*)d_in[0];   // [16,2048,256]
    const float* graph = (const float*)d_in[1];   // [1,2048,2048]
    const float* W     = (const float*)d_in[2];   // [256,256]
    const float* bias  = (const float*)d_in[3];   // [256]
    float* out = (float*)d_out;

    char* ws = (char*)d_ws;
    float*          dinv = (float*)ws;                                   // 8 KB
    uint8_t*        gq   = (uint8_t*)(ws + 8192);                        // 4 MB
    unsigned short* Wt   = (unsigned short*)(ws + 8192 + 4194304);       // 128 KB
    uint8_t*        Pq   = (uint8_t*)(ws + 8192 + 4194304 + 131072);     // 8 MB

    prep_graph<<<LL, 256, 0, stream>>>(graph, dinv, gq);
    prep_w<<<DD, 256, 0, stream>>>(W, Wt);
    linear_kernel<<<dim3((NB * LL) / 128, DD / 128), 256, 0, stream>>>(x, Wt, dinv, Pq);
    agg_kernel<<<512, 256, 0, stream>>>(gq, Pq, dinv, bias, x, out);
}